// Round 13
// baseline (703.748 us; speedup 1.0000x reference)
//
#include <hip/hip_runtime.h>
#include <hip/hip_bf16.h>

#define P     10
#define NTOK  59
#define HEADS 12
#define NWTOK 49

#define AW_OFF 38535168   // frozen: verified by 11 passing rounds
#define PO_OFF 124096512  // frozen: verified by 11 passing rounds

typedef __attribute__((ext_vector_type(8))) short short8;
typedef __attribute__((ext_vector_type(8))) unsigned short ushort8;
typedef __attribute__((ext_vector_type(4))) float floatx4;
typedef float f4u __attribute__((ext_vector_type(4), aligned(4)));
typedef unsigned int uint_g __attribute__((address_space(1)));
typedef unsigned int uint_l __attribute__((address_space(3)));

__device__ __forceinline__ unsigned short f2b(float f) {
  unsigned u = __builtin_bit_cast(unsigned, f);
  u += 0x7fffu + ((u >> 16) & 1u);
  return (unsigned short)(u >> 16);
}

__device__ __forceinline__ void gll16(const void* g, void* l) {
  __builtin_amdgcn_global_load_lds((const uint_g*)g, (uint_l*)l, 16, 0, 0);
}

// bijective XCD-aware block swizzle (m204 form)
__device__ __forceinline__ int xcd_swz(int bid, int nwg) {
  const int q = nwg >> 3, r = nwg & 7;
  const int xcd = bid & 7, ord = bid >> 3;
  return (xcd < r ? xcd * (q + 1) : r * (q + 1) + (xcd - r) * q) + ord;
}

// ---------------------------------------------------------------------------
// convert f32 -> bf16 flat (grid sized exactly: n/8/256 blocks)
// ---------------------------------------------------------------------------
__global__ __launch_bounds__(256) void convert_w_kernel(
    const float* __restrict__ w, unsigned short* __restrict__ wb) {
  const int i = (blockIdx.x * 256 + threadIdx.x) * 8;
  const float4 a = *(const float4*)(w + i);
  const float4 b = *(const float4*)(w + i + 4);
  ushort8 o;
  o[0] = f2b(a.x); o[1] = f2b(a.y); o[2] = f2b(a.z); o[3] = f2b(a.w);
  o[4] = f2b(b.x); o[5] = f2b(b.y); o[6] = f2b(b.z); o[7] = f2b(b.w);
  *(ushort8*)(wb + i) = o;
}

// ---------------------------------------------------------------------------
// combo[wnd][h][64][64]: padded with zeros outside the 49x49 valid region.
// ---------------------------------------------------------------------------
__global__ __launch_bounds__(256) void combo_kernel(
    const float* __restrict__ mask, const float* __restrict__ bias_table,
    float* __restrict__ combo) {
  const int bid = blockIdx.x;          // wnd*12 + h
  const int h = bid % HEADS, wnd = bid / HEADS;
#pragma unroll
  for (int e0 = 0; e0 < 4096; e0 += 256) {
    const int e = e0 + threadIdx.x;
    const int ti = e >> 6, tj = e & 63;
    float v = 0.f;
    if (ti >= P && ti < NTOK && tj >= P && tj < NTOK) {
      const int a = ti - P, c = tj - P;
      const int ai = a / 7, aj = a - ai * 7;
      const int bi = c / 7, bj = c - bi * 7;
      const int ridx = (ai - bi + 6) * 13 + (aj - bj + 6);
      v = bias_table[ridx * HEADS + h] + mask[((size_t)wnd * 49 + a) * 49 + c];
    }
    combo[((size_t)bid << 12) + e] = v;
  }
}

// ---------------------------------------------------------------------------
// QKV GEMM (proven R8-R12 form): A/B via global_load_lds, bf16 inputs.
// Output row-contiguous qkx[bb][sec][tok49][384], qkp[b0][sec][tok10][384].
// ---------------------------------------------------------------------------
__global__ __launch_bounds__(256) void gemm_qkv_kernel(
    const unsigned short* __restrict__ xb, const unsigned short* __restrict__ xp,
    const unsigned short* __restrict__ Bw, const float* __restrict__ b_qkv,
    unsigned short* __restrict__ qkx, unsigned short* __restrict__ qkp) {
  __shared__ unsigned short sbuf[18432];   // Asw|Bsw, reused as repack
  unsigned short* Asw = sbuf;
  unsigned short* Bsw = sbuf + 8192;
  const int t = threadIdx.x;
  const int w = t >> 6, lane = t & 63;
  const int lr = lane & 15, lg = lane >> 4;
  const int w0 = w >> 1, w1 = w & 1;
  const int wg = xcd_swz(blockIdx.x, 9 * 787);
  const int cb = wg % 9;          // column block 0..8
  const int my = wg / 9;          // row block 0..786
  const bool isP = my >= 784;
  const int n0 = cb * 128;
  const int srow = lane >> 3, cpos = lane & 7;

  floatx4 acc[4][4];
#pragma unroll
  for (int mr = 0; mr < 4; ++mr)
#pragma unroll
    for (int nc = 0; nc < 4; ++nc) acc[mr][nc] = (floatx4)0.f;

  for (int k0 = 0; k0 < 384; k0 += 64) {
#pragma unroll
    for (int i = 0; i < 4; ++i) {
      const int r = (w * 4 + i) * 8 + srow;
      const int c = cpos ^ (r & 7);
      const unsigned short* asrc;
      if (!isP) {
        asrc = xb + (size_t)(my * 128 + r) * 384 + k0 + c * 8;
      } else {
        int mp = (my - 784) * 128 + r;
        if (mp > 319) mp = 319;
        asrc = xp + (size_t)mp * 384 + k0 + c * 8;
      }
      gll16(asrc, Asw + (w * 4 + i) * 512);
      gll16(Bw + (size_t)(n0 + r) * 384 + k0 + c * 8, Bsw + (w * 4 + i) * 512);
    }
    __syncthreads();
#pragma unroll
    for (int kh = 0; kh < 2; ++kh) {
      short8 af[4], bf[4];
#pragma unroll
      for (int mr = 0; mr < 4; ++mr) {
        const int r = w0 * 64 + mr * 16 + lr;
        af[mr] = *(const short8*)(Asw + r * 64 + (((kh * 4 + lg) ^ (r & 7)) * 8));
      }
#pragma unroll
      for (int nc = 0; nc < 4; ++nc) {
        const int r = w1 * 64 + nc * 16 + lr;
        bf[nc] = *(const short8*)(Bsw + r * 64 + (((kh * 4 + lg) ^ (r & 7)) * 8));
      }
#pragma unroll
      for (int mr = 0; mr < 4; ++mr)
#pragma unroll
        for (int nc = 0; nc < 4; ++nc)
          acc[mr][nc] = __builtin_amdgcn_mfma_f32_16x16x32_bf16(
              af[mr], bf[nc], acc[mr][nc], 0, 0, 0);
    }
    __syncthreads();
  }

  // ---- epilogue: +bias, per-wave 64x64 LDS repack, 128B/lane stores ----
  const int sec = cb / 3;
  const int nis = (cb - sec * 3) * 128;
  float bias[4];
#pragma unroll
  for (int nc = 0; nc < 4; ++nc)
    bias[nc] = b_qkv[n0 + w1 * 64 + nc * 16 + lr];

  unsigned short* rp = sbuf + w * 4608;   // own wave: [64][72]
#pragma unroll
  for (int mr = 0; mr < 4; ++mr)
#pragma unroll
    for (int nc = 0; nc < 4; ++nc)
#pragma unroll
      for (int reg = 0; reg < 4; ++reg)
        rp[(mr * 16 + lg * 4 + reg) * 72 + nc * 16 + lr] =
            f2b(acc[mr][nc][reg] + bias[nc]);
  __syncthreads();

  const int rr = lane;
  unsigned short* dst = nullptr;
  if (!isP) {
    const int m = my * 128 + w0 * 64 + rr;
    const int bb = m / 49, tok = m - bb * 49;
    dst = qkx + ((size_t)(bb * 3 + sec) * 49 + tok) * 384 + nis + w1 * 64;
  } else {
    const int mp = (my - 784) * 128 + w0 * 64 + rr;
    if (mp < 320) {
      const int b0 = mp / 10, ptok = mp - b0 * 10;
      dst = qkp + ((size_t)(b0 * 3 + sec) * 10 + ptok) * 384 + nis + w1 * 64;
    }
  }
  if (dst) {
#pragma unroll
    for (int u = 0; u < 8; ++u)
      *(ushort8*)(dst + u * 8) = *(const ushort8*)(rp + rr * 72 + u * 8);
  }
}

// ---------------------------------------------------------------------------
// FUSED attention + per-head proj accumulation. 2048 blocks (one per window),
// 4 waves. Per head: stage q/k (gll16, 2-way-free swizzle) + wB (gll16) +
// vt (T14 reg, issued AFTER barrier so loads ride under compute) ->
// swapped QK^T -> reg aw store -> in-reg softmax -> shfl P -> swapped PV ->
// shfl O -> 24 proj MFMA into persistent pacc. 2 barriers/head.
// LDS 37504 B; VGPR target <=170 (launch_bounds 256,3).
// ---------------------------------------------------------------------------
__global__ __launch_bounds__(256, 3) void attn_proj_kernel(
    const unsigned short* __restrict__ qkx, const unsigned short* __restrict__ qkp,
    const float* __restrict__ combo, const unsigned short* __restrict__ wproj,
    const float* __restrict__ b_proj, float* __restrict__ aw_out,
    float* __restrict__ x_out, float* __restrict__ pbuf) {
  __shared__ char lds[37504];
  unsigned short* qs = (unsigned short*)(lds);          // [64][32] swz
  unsigned short* ks = (unsigned short*)(lds + 4096);   // [64][32] swz
  unsigned short* vt = (unsigned short*)(lds + 8192);   // [32][74] V^T
  unsigned short* wB = (unsigned short*)(lds + 12928);  // [384][32] swz

  const int b = xcd_swz(blockIdx.x, 2048);  // 256 consecutive windows per XCD
  const int t = threadIdx.x;
  const int w = t >> 6, lane = t & 63, lr = lane & 15, lg = lane >> 4;
  const float scale = 0.17677669529663687f;
  const int q = w * 16 + lr;

  // gll16 per-lane coords for qs/ks (group = own wave's 16 rows)
  const int gr = w * 16 + (lane >> 2);
  const int gc = (lane & 3) ^ ((gr >> 1) & 3);

  // T14 reg-stage for V (transpose scatter can't use gll16)
  ushort8 nv;
  const int srow_ = t >> 2, sdc = (t & 3) * 8;
  auto load_v = [&](int h) {
    if (t < 236) {
      if (srow_ < P)
        nv = *(const ushort8*)(qkp +
            ((size_t)((b >> 6) * 3 + 2) * 10 + srow_) * 384 + h * 32 + sdc);
      else
        nv = *(const ushort8*)(qkx +
            ((size_t)(b * 3 + 2) * 49 + (srow_ - P)) * 384 + h * 32 + sdc);
    }
  };

  if (t < 160) vt[(t / 5) * 74 + 59 + (t % 5)] = 0;   // pad cols persist
  load_v(0);

  floatx4 pacc[24];
#pragma unroll
  for (int nc = 0; nc < 24; ++nc) pacc[nc] = (floatx4)0.f;

  for (int h = 0; h < HEADS; ++h) {
    __syncthreads();   // prev head's LDS reads done (also drains load_v)
    if (t < 236) {
#pragma unroll
      for (int j = 0; j < 8; ++j) vt[(sdc + j) * 74 + srow_] = nv[j];
    }
    // qs/ks via gll16 (per-lane source; rows>=59 read in-bounds garbage,
    // masked downstream exactly as rounds 4-11)
    {
      const unsigned short *qsrc, *ksrc;
      if (gr < P) {
        const size_t pb =
            ((size_t)((b >> 6) * 3) * 10 + gr) * 384 + h * 32 + gc * 8;
        qsrc = qkp + pb;
        ksrc = qkp + pb + 10 * 384;
      } else {
        const size_t xb_ =
            ((size_t)(b * 3) * 49 + (gr - P)) * 384 + h * 32 + gc * 8;
        qsrc = qkx + xb_;
        ksrc = qkx + xb_ + 49 * 384;
      }
      gll16(qsrc, qs + w * 512);
      gll16(ksrc, ks + w * 512);
    }
    // wB via gll16: 24 groups of 16 rows (6 per wave)
#pragma unroll
    for (int i = 0; i < 6; ++i) {
      const int g = w * 6 + i;
      const int r = g * 16 + (lane >> 2);
      const int c = (lane & 3) ^ ((r >> 1) & 3);
      gll16(wproj + (size_t)r * 384 + h * 32 + c * 8, wB + g * 512);
    }
    __syncthreads();   // drains gll16 + vt ds_writes
    if (h + 1 < HEADS) load_v(h + 1);   // outstanding across compute below

    // ---- swapped QK^T: lane holds S[q][kk] ----
    const short8 qa = *(const short8*)(qs + q * 32 + ((lg ^ ((q >> 1) & 3)) * 8));
    floatx4 sacc[4];
#pragma unroll
    for (int nt = 0; nt < 4; ++nt) {
      const int rk = nt * 16 + lr;
      const short8 kb =
          *(const short8*)(ks + rk * 32 + ((lg ^ ((rk >> 1) & 3)) * 8));
      sacc[nt] =
          __builtin_amdgcn_mfma_f32_16x16x32_bf16(kb, qa, (floatx4)0.f, 0, 0, 0);
    }

    // ---- raw S from registers ----
    if (q < NTOK) {
      float* rowp = aw_out + ((size_t)(b * HEADS + h)) * 3481 + q * 59;
#pragma unroll
      for (int nt = 0; nt < 3; ++nt)
        *(f4u*)(rowp + nt * 16 + lg * 4) = __builtin_bit_cast(f4u, sacc[nt]);
      if (lg < 2) {
        *(f4u*)(rowp + 48 + lg * 4) = __builtin_bit_cast(f4u, sacc[3]);
      } else if (lg == 2) {
        rowp[56] = sacc[3][0]; rowp[57] = sacc[3][1]; rowp[58] = sacc[3][2];
      }
    }

    // ---- in-register softmax (exp written back into sacc) ----
    const float* comb =
        combo + (((size_t)((b & 63) * HEADS + h)) << 12) + q * 64;
    float mx = -3.0e38f;
#pragma unroll
    for (int nt = 0; nt < 4; ++nt) {
      const float4 c4 = *(const float4*)(comb + nt * 16 + lg * 4);
      const float cc[4] = {c4.x, c4.y, c4.z, c4.w};
#pragma unroll
      for (int reg = 0; reg < 4; ++reg) {
        const int kk2 = nt * 16 + lg * 4 + reg;
        const float v = (q < NTOK && kk2 < NTOK)
                            ? fmaf(sacc[nt][reg], scale, cc[reg])
                            : -3.0e38f;
        sacc[nt][reg] = v;
        mx = fmaxf(mx, v);
      }
    }
    mx = fmaxf(mx, __shfl_xor(mx, 16));
    mx = fmaxf(mx, __shfl_xor(mx, 32));
    float sm = 0.f;
#pragma unroll
    for (int nt = 0; nt < 4; ++nt)
#pragma unroll
      for (int reg = 0; reg < 4; ++reg) {
        const float e = __expf(sacc[nt][reg] - mx);
        sacc[nt][reg] = e;
        sm += e;
      }
    sm += __shfl_xor(sm, 16);
    sm += __shfl_xor(sm, 32);
    const float inv = 1.0f / sm;

    // pack P pairs
    unsigned pk[4][2];
#pragma unroll
    for (int nt = 0; nt < 4; ++nt)
#pragma unroll
      for (int pp = 0; pp < 2; ++pp)
        pk[nt][pp] = (unsigned)f2b(sacc[nt][2 * pp] * inv) |
                     ((unsigned)f2b(sacc[nt][2 * pp + 1] * inv) << 16);

    // ---- swapped PV: oaccT[nt][reg] = O[q=w*16+lr][d=nt*16+lg*4+reg] ----
    floatx4 oaccT[2];
    oaccT[0] = (floatx4)0.f; oaccT[1] = (floatx4)0.f;
#pragma unroll
    for (int kk = 0; kk < 2; ++kk) {
      unsigned W4[4];
#pragma unroll
      for (int jp = 0; jp < 4; ++jp) {
        const int srcl = lr + 16 * (2 * (lg & 1) + (jp >> 1));
        const int lo = __shfl((int)pk[2 * kk][jp & 1], srcl);
        const int hi = __shfl((int)pk[2 * kk + 1][jp & 1], srcl);
        W4[jp] = (lg >> 1) ? (unsigned)hi : (unsigned)lo;
      }
      uint4 wu; wu.x = W4[0]; wu.y = W4[1]; wu.z = W4[2]; wu.w = W4[3];
      const short8 pa = __builtin_bit_cast(short8, wu);
#pragma unroll
      for (int nt = 0; nt < 2; ++nt) {
        const short8 vb =
            *(const short8*)(vt + (nt * 16 + lr) * 74 + kk * 32 + lg * 8);
        oaccT[nt] =
            __builtin_amdgcn_mfma_f32_16x16x32_bf16(vb, pa, oaccT[nt], 0, 0, 0);
      }
    }

    // ---- O pack + shfl (kk=0 instance of the same pattern) -> proj A ----
    unsigned pko[2][2];
#pragma unroll
    for (int nt = 0; nt < 2; ++nt)
#pragma unroll
      for (int pp = 0; pp < 2; ++pp)
        pko[nt][pp] = (unsigned)f2b(oaccT[nt][2 * pp]) |
                      ((unsigned)f2b(oaccT[nt][2 * pp + 1]) << 16);
    unsigned W4[4];
#pragma unroll
    for (int jp = 0; jp < 4; ++jp) {
      const int srcl = lr + 16 * (2 * (lg & 1) + (jp >> 1));
      const int lo = __shfl((int)pko[0][jp & 1], srcl);
      const int hi = __shfl((int)pko[1][jp & 1], srcl);
      W4[jp] = (lg >> 1) ? (unsigned)hi : (unsigned)lo;
    }
    uint4 wu; wu.x = W4[0]; wu.y = W4[1]; wu.z = W4[2]; wu.w = W4[3];
    const short8 af_o = __builtin_bit_cast(short8, wu);

    // ---- proj: pacc[nc] += O_h @ Wproj_h^T (k-order == heads ascending) ----
#pragma unroll
    for (int nc = 0; nc < 24; ++nc) {
      const int r = nc * 16 + lr;
      const short8 bfw =
          *(const short8*)(wB + r * 32 + ((lg ^ ((r >> 1) & 3)) * 8));
      pacc[nc] =
          __builtin_amdgcn_mfma_f32_16x16x32_bf16(af_o, bfw, pacc[nc], 0, 0, 0);
    }
  }

  // ---- epilogue: +bias, routed f32 stores (rows w*16+lg*4+reg) ----
#pragma unroll
  for (int nc = 0; nc < 24; ++nc) {
    const int n = nc * 16 + lr;
    const float bias = b_proj[n];
#pragma unroll
    for (int reg = 0; reg < 4; ++reg) {
      const int row = w * 16 + lg * 4 + reg;
      if (row < NTOK) {
        float* dst = (row >= P)
            ? x_out + ((size_t)(b * NWTOK + row - P)) * 384 + n
            : pbuf + ((size_t)(b * P + row)) * 384 + n;
        *dst = pacc[nc][reg] + bias;
      }
    }
  }
}

// ---------------------------------------------------------------------------
// prompts_out = mean over 64 windows
// ---------------------------------------------------------------------------
__global__ __launch_bounds__(256) void reduce_prompts_kernel(
    const float* __restrict__ pbuf, float* __restrict__ po) {
  const int o = blockIdx.x * 256 + threadIdx.x;  // < 32*10*384
  const int b0 = o / 3840;
  const int rem = o - b0 * 3840;
  const float* base = pbuf + (size_t)b0 * 64 * 3840 + rem;
  float s = 0.f;
#pragma unroll 8
  for (int w = 0; w < 64; ++w) s += base[(size_t)w * 3840];
  po[o] = s * (1.f / 64.f);
}

extern "C" void kernel_launch(void* const* d_in, const int* in_sizes, int n_in,
                              void* d_out, int out_size, void* d_ws, size_t ws_size,
                              hipStream_t stream) {
  const float* x          = (const float*)d_in[0];
  const float* spa        = (const float*)d_in[1];
  const float* mask       = (const float*)d_in[2];
  const float* bias_table = (const float*)d_in[3];
  const float* w_qkv      = (const float*)d_in[4];
  const float* b_qkv      = (const float*)d_in[5];
  const float* w_proj     = (const float*)d_in[6];
  const float* b_proj     = (const float*)d_in[7];
  float* out = (float*)d_out;

  // ws layout (bytes):
  // [0, 77070336)            x_bf  (bf16 100352x384)  (consumed by gemm_qkv)
  // [77070336, 77316096)     xp_bf (bf16 320x384)
  // [77316096, 78200832)     wqkv_bf
  // [92798976, 324009984)    qkx (bf16 [2048][3][49][384])
  // [324009984, 324747264)   qkp (bf16 [32][3][10][384])
  // [324747264, 325042176)   wproj_bf
  // [325042176, 356499456)   pbuf  (f32 2048*10*384)
  // [356499456, 369082368)   combo (f32 [64][12][64][64])
  unsigned short* x_bf     = (unsigned short*)d_ws;
  unsigned short* xp_bf    = (unsigned short*)((char*)d_ws + 77070336ULL);
  unsigned short* wqkv_bf  = (unsigned short*)((char*)d_ws + 77316096ULL);
  unsigned short* qkx      = (unsigned short*)((char*)d_ws + 92798976ULL);
  unsigned short* qkp      = (unsigned short*)((char*)d_ws + 324009984ULL);
  unsigned short* wproj_bf = (unsigned short*)((char*)d_ws + 324747264ULL);
  float*          pbuf     = (float*)((char*)d_ws + 325042176ULL);
  float*          combo    = (float*)((char*)d_ws + 356499456ULL);

  convert_w_kernel<<<18816, 256, 0, stream>>>(x, x_bf);
  convert_w_kernel<<<60, 256, 0, stream>>>(spa, xp_bf);
  convert_w_kernel<<<216, 256, 0, stream>>>(w_qkv, wqkv_bf);
  convert_w_kernel<<<72, 256, 0, stream>>>(w_proj, wproj_bf);
  combo_kernel<<<768, 256, 0, stream>>>(mask, bias_table, combo);
  gemm_qkv_kernel<<<9 * 787, 256, 0, stream>>>(x_bf, xp_bf, wqkv_bf, b_qkv,
                                               qkx, qkp);
  attn_proj_kernel<<<2048, 256, 0, stream>>>(qkx, qkp, combo, wproj_bf, b_proj,
                                             out + AW_OFF, out, pbuf);
  reduce_prompts_kernel<<<480, 256, 0, stream>>>(pbuf, out + PO_OFF);
}

// Round 14
// 588.534 us; speedup vs baseline: 1.1958x; 1.1958x over previous
//
#include <hip/hip_runtime.h>
#include <hip/hip_bf16.h>

#define P     10
#define NTOK  59
#define HEADS 12
#define NWTOK 49

#define AW_OFF 38535168   // frozen: verified by 12 passing rounds
#define PO_OFF 124096512  // frozen: verified by 12 passing rounds

typedef __attribute__((ext_vector_type(8))) short short8;
typedef __attribute__((ext_vector_type(8))) unsigned short ushort8;
typedef __attribute__((ext_vector_type(4))) float floatx4;
typedef float f4u __attribute__((ext_vector_type(4), aligned(4)));
typedef unsigned int uint_g __attribute__((address_space(1)));
typedef unsigned int uint_l __attribute__((address_space(3)));

__device__ __forceinline__ unsigned short f2b(float f) {
  unsigned u = __builtin_bit_cast(unsigned, f);
  u += 0x7fffu + ((u >> 16) & 1u);
  return (unsigned short)(u >> 16);
}

__device__ __forceinline__ void gll16(const void* g, void* l) {
  __builtin_amdgcn_global_load_lds((const uint_g*)g, (uint_l*)l, 16, 0, 0);
}

// bijective XCD-aware block swizzle (m204 form)
__device__ __forceinline__ int xcd_swz(int bid, int nwg) {
  const int q = nwg >> 3, r = nwg & 7;
  const int xcd = bid & 7, ord = bid >> 3;
  return (xcd < r ? xcd * (q + 1) : r * (q + 1) + (xcd - r) * q) + ord;
}

// ---------------------------------------------------------------------------
// merged convert f32 -> bf16: x | spa | w_qkv | w_proj in one launch
// ---------------------------------------------------------------------------
__global__ __launch_bounds__(256) void convert_all_kernel(
    const float* __restrict__ x, const float* __restrict__ spa,
    const float* __restrict__ wq, const float* __restrict__ wp,
    unsigned short* __restrict__ xb, unsigned short* __restrict__ xpb,
    unsigned short* __restrict__ wqb, unsigned short* __restrict__ wpb) {
  const int bid = blockIdx.x;
  const float* src; unsigned short* dst; int base;
  if (bid < 18816)      { src = x;   dst = xb;  base = bid; }
  else if (bid < 18876) { src = spa; dst = xpb; base = bid - 18816; }
  else if (bid < 19092) { src = wq;  dst = wqb; base = bid - 18876; }
  else                  { src = wp;  dst = wpb; base = bid - 19092; }
  const int i = (base * 256 + threadIdx.x) * 8;
  const float4 a = *(const float4*)(src + i);
  const float4 b = *(const float4*)(src + i + 4);
  ushort8 o;
  o[0] = f2b(a.x); o[1] = f2b(a.y); o[2] = f2b(a.z); o[3] = f2b(a.w);
  o[4] = f2b(b.x); o[5] = f2b(b.y); o[6] = f2b(b.z); o[7] = f2b(b.w);
  *(ushort8*)(dst + i) = o;
}

// ---------------------------------------------------------------------------
// combo[wnd][h][64][64]: padded with zeros outside the 49x49 valid region.
// ---------------------------------------------------------------------------
__global__ __launch_bounds__(256) void combo_kernel(
    const float* __restrict__ mask, const float* __restrict__ bias_table,
    float* __restrict__ combo) {
  const int bid = blockIdx.x;          // wnd*12 + h
  const int h = bid % HEADS, wnd = bid / HEADS;
#pragma unroll
  for (int e0 = 0; e0 < 4096; e0 += 256) {
    const int e = e0 + threadIdx.x;
    const int ti = e >> 6, tj = e & 63;
    float v = 0.f;
    if (ti >= P && ti < NTOK && tj >= P && tj < NTOK) {
      const int a = ti - P, c = tj - P;
      const int ai = a / 7, aj = a - ai * 7;
      const int bi = c / 7, bj = c - bi * 7;
      const int ridx = (ai - bi + 6) * 13 + (aj - bj + 6);
      v = bias_table[ridx * HEADS + h] + mask[((size_t)wnd * 49 + a) * 49 + c];
    }
    combo[((size_t)bid << 12) + e] = v;
  }
}

// ---------------------------------------------------------------------------
// QKV GEMM (proven R8-R11 form): A/B via global_load_lds, bf16 inputs.
// Output row-contiguous qkx[bb][sec][tok49][384], qkp[b0][sec][tok10][384].
// ---------------------------------------------------------------------------
__global__ __launch_bounds__(256) void gemm_qkv_kernel(
    const unsigned short* __restrict__ xb, const unsigned short* __restrict__ xp,
    const unsigned short* __restrict__ Bw, const float* __restrict__ b_qkv,
    unsigned short* __restrict__ qkx, unsigned short* __restrict__ qkp) {
  __shared__ unsigned short sbuf[18432];   // Asw|Bsw, reused as repack
  unsigned short* Asw = sbuf;
  unsigned short* Bsw = sbuf + 8192;
  const int t = threadIdx.x;
  const int w = t >> 6, lane = t & 63;
  const int lr = lane & 15, lg = lane >> 4;
  const int w0 = w >> 1, w1 = w & 1;
  const int wg = xcd_swz(blockIdx.x, 9 * 787);
  const int cb = wg % 9;          // column block 0..8
  const int my = wg / 9;          // row block 0..786
  const bool isP = my >= 784;
  const int n0 = cb * 128;
  const int srow = lane >> 3, cpos = lane & 7;

  floatx4 acc[4][4];
#pragma unroll
  for (int mr = 0; mr < 4; ++mr)
#pragma unroll
    for (int nc = 0; nc < 4; ++nc) acc[mr][nc] = (floatx4)0.f;

  for (int k0 = 0; k0 < 384; k0 += 64) {
#pragma unroll
    for (int i = 0; i < 4; ++i) {
      const int r = (w * 4 + i) * 8 + srow;
      const int c = cpos ^ (r & 7);
      const unsigned short* asrc;
      if (!isP) {
        asrc = xb + (size_t)(my * 128 + r) * 384 + k0 + c * 8;
      } else {
        int mp = (my - 784) * 128 + r;
        if (mp > 319) mp = 319;
        asrc = xp + (size_t)mp * 384 + k0 + c * 8;
      }
      gll16(asrc, Asw + (w * 4 + i) * 512);
      gll16(Bw + (size_t)(n0 + r) * 384 + k0 + c * 8, Bsw + (w * 4 + i) * 512);
    }
    __syncthreads();
#pragma unroll
    for (int kh = 0; kh < 2; ++kh) {
      short8 af[4], bf[4];
#pragma unroll
      for (int mr = 0; mr < 4; ++mr) {
        const int r = w0 * 64 + mr * 16 + lr;
        af[mr] = *(const short8*)(Asw + r * 64 + (((kh * 4 + lg) ^ (r & 7)) * 8));
      }
#pragma unroll
      for (int nc = 0; nc < 4; ++nc) {
        const int r = w1 * 64 + nc * 16 + lr;
        bf[nc] = *(const short8*)(Bsw + r * 64 + (((kh * 4 + lg) ^ (r & 7)) * 8));
      }
#pragma unroll
      for (int mr = 0; mr < 4; ++mr)
#pragma unroll
        for (int nc = 0; nc < 4; ++nc)
          acc[mr][nc] = __builtin_amdgcn_mfma_f32_16x16x32_bf16(
              af[mr], bf[nc], acc[mr][nc], 0, 0, 0);
    }
    __syncthreads();
  }

  // ---- epilogue: +bias, per-wave 64x64 LDS repack, 128B/lane stores ----
  const int sec = cb / 3;
  const int nis = (cb - sec * 3) * 128;
  float bias[4];
#pragma unroll
  for (int nc = 0; nc < 4; ++nc)
    bias[nc] = b_qkv[n0 + w1 * 64 + nc * 16 + lr];

  unsigned short* rp = sbuf + w * 4608;   // own wave: [64][72]
#pragma unroll
  for (int mr = 0; mr < 4; ++mr)
#pragma unroll
    for (int nc = 0; nc < 4; ++nc)
#pragma unroll
      for (int reg = 0; reg < 4; ++reg)
        rp[(mr * 16 + lg * 4 + reg) * 72 + nc * 16 + lr] =
            f2b(acc[mr][nc][reg] + bias[nc]);
  __syncthreads();

  const int rr = lane;
  unsigned short* dst = nullptr;
  if (!isP) {
    const int m = my * 128 + w0 * 64 + rr;
    const int bb = m / 49, tok = m - bb * 49;
    dst = qkx + ((size_t)(bb * 3 + sec) * 49 + tok) * 384 + nis + w1 * 64;
  } else {
    const int mp = (my - 784) * 128 + w0 * 64 + rr;
    if (mp < 320) {
      const int b0 = mp / 10, ptok = mp - b0 * 10;
      dst = qkp + ((size_t)(b0 * 3 + sec) * 10 + ptok) * 384 + nis + w1 * 64;
    }
  }
  if (dst) {
#pragma unroll
    for (int u = 0; u < 8; ++u)
      *(ushort8*)(dst + u * 8) = *(const ushort8*)(rp + rr * 72 + u * 8);
  }
}

// ---------------------------------------------------------------------------
// FUSED attention + proj (R11 structure). 2048 blocks, 4 waves, LDS 74752.
// T14 FIX: prefetches issued AFTER the post-staging barrier, so the
// compiler's vmcnt(0)-before-s_barrier drain no longer kills the overlap.
// ---------------------------------------------------------------------------
__global__ __launch_bounds__(256) void attn_proj_kernel(
    const unsigned short* __restrict__ qkx, const unsigned short* __restrict__ qkp,
    const float* __restrict__ combo, const unsigned short* __restrict__ wproj,
    const float* __restrict__ b_proj, float* __restrict__ aw_out,
    float* __restrict__ x_out, float* __restrict__ pbuf) {
  __shared__ char lds[74752];
  unsigned short* Obuf = (unsigned short*)lds;             // [64][392] bf16
  unsigned short* qs   = (unsigned short*)(lds + 50176);   // [64][40]
  unsigned short* ks   = (unsigned short*)(lds + 55296);   // [64][40]
  unsigned short* vt   = (unsigned short*)(lds + 60416);   // [32][74] V^T
  unsigned short* Bst  = (unsigned short*)(lds + 50176);   // proj: [192][64]

  const int b = blockIdx.x;
  const int t = threadIdx.x;
  const int w = t >> 6, lane = t & 63, lr = lane & 15, lg = lane >> 4;
  const float scale = 0.17677669529663687f;
  const int q = w * 16 + lr;

  // staging registers (T14: issue-early / write-late)
  ushort8 nq, nk, nv;
  const int srow_ = t >> 2, sdc = (t & 3) * 8;
  auto load_head = [&](int h) {
    if (t < 236) {
      if (srow_ < P) {
        const unsigned short* pb =
            qkp + ((size_t)((b >> 6) * 3) * 10 + srow_) * 384 + h * 32 + sdc;
        nq = *(const ushort8*)(pb);
        nk = *(const ushort8*)(pb + 10 * 384);
        nv = *(const ushort8*)(pb + 20 * 384);
      } else {
        const unsigned short* xbp =
            qkx + ((size_t)(b * 3) * 49 + (srow_ - P)) * 384 + h * 32 + sdc;
        nq = *(const ushort8*)(xbp);
        nk = *(const ushort8*)(xbp + 49 * 384);
        nv = *(const ushort8*)(xbp + 98 * 384);
      }
    }
  };

  // prologue: zero vt pad cols (persist across heads), load head 0
  if (t < 160) vt[(t / 5) * 74 + 59 + (t % 5)] = 0;
  load_head(0);

  // ================= attention: 12 head rounds =================
  for (int h = 0; h < HEADS; ++h) {
    __syncthreads();   // staging region free (prev round's PV reads done)
    if (t < 236) {
      *(ushort8*)(qs + srow_ * 40 + sdc) = nq;
      *(ushort8*)(ks + srow_ * 40 + sdc) = nk;
#pragma unroll
      for (int j = 0; j < 8; ++j) vt[(sdc + j) * 74 + srow_] = nv[j];
    }
    __syncthreads();
    // T14 fixed placement: issue AFTER the barrier so the drain-before-
    // s_barrier doesn't serialize the prefetch; nq/nk/nv are dead here.
    if (h + 1 < HEADS) load_head(h + 1);

    // swapped QK^T: lane holds S[q][kk]
    const short8 qa = *(const short8*)(qs + q * 40 + lg * 8);
    floatx4 sacc[4];
#pragma unroll
    for (int nt = 0; nt < 4; ++nt) {
      const short8 kb = *(const short8*)(ks + (nt * 16 + lr) * 40 + lg * 8);
      sacc[nt] =
          __builtin_amdgcn_mfma_f32_16x16x32_bf16(kb, qa, (floatx4)0.f, 0, 0, 0);
    }

    // raw S straight from registers
    if (q < NTOK) {
      float* rowp = aw_out + ((size_t)(b * HEADS + h)) * 3481 + q * 59;
#pragma unroll
      for (int nt = 0; nt < 3; ++nt)
        *(f4u*)(rowp + nt * 16 + lg * 4) = __builtin_bit_cast(f4u, sacc[nt]);
      if (lg < 2) {
        *(f4u*)(rowp + 48 + lg * 4) = __builtin_bit_cast(f4u, sacc[3]);
      } else if (lg == 2) {
        rowp[56] = sacc[3][0]; rowp[57] = sacc[3][1]; rowp[58] = sacc[3][2];
      }
    }

    // in-register softmax
    const float* comb =
        combo + (((size_t)((b & 63) * HEADS + h)) << 12) + q * 64;
    float ev[4][4];
    float mx = -3.0e38f;
#pragma unroll
    for (int nt = 0; nt < 4; ++nt) {
      const float4 c4 = *(const float4*)(comb + nt * 16 + lg * 4);
      const float cc[4] = {c4.x, c4.y, c4.z, c4.w};
#pragma unroll
      for (int reg = 0; reg < 4; ++reg) {
        const int kk2 = nt * 16 + lg * 4 + reg;
        const float v = (q < NTOK && kk2 < NTOK)
                            ? fmaf(sacc[nt][reg], scale, cc[reg])
                            : -3.0e38f;
        ev[nt][reg] = v;
        mx = fmaxf(mx, v);
      }
    }
    mx = fmaxf(mx, __shfl_xor(mx, 16));
    mx = fmaxf(mx, __shfl_xor(mx, 32));
    float sm = 0.f;
#pragma unroll
    for (int nt = 0; nt < 4; ++nt)
#pragma unroll
      for (int reg = 0; reg < 4; ++reg) {
        const float e = __expf(ev[nt][reg] - mx);
        ev[nt][reg] = e;
        sm += e;
      }
    sm += __shfl_xor(sm, 16);
    sm += __shfl_xor(sm, 32);
    const float inv = 1.0f / sm;

    // pack P pairs: pk[nt][pp] = P[q][nt*16+lg*4+2pp..+1]
    unsigned pk[4][2];
#pragma unroll
    for (int nt = 0; nt < 4; ++nt)
#pragma unroll
      for (int pp = 0; pp < 2; ++pp)
        pk[nt][pp] = (unsigned)f2b(ev[nt][2 * pp] * inv) |
                     ((unsigned)f2b(ev[nt][2 * pp + 1] * inv) << 16);

    // shfl redistribution to MFMA A-layout, then PV
    floatx4 oacc[2];
    oacc[0] = (floatx4)0.f; oacc[1] = (floatx4)0.f;
#pragma unroll
    for (int kk = 0; kk < 2; ++kk) {
      unsigned W4[4];
#pragma unroll
      for (int jp = 0; jp < 4; ++jp) {
        const int srcl = lr + 16 * (2 * (lg & 1) + (jp >> 1));
        const int lo = __shfl((int)pk[2 * kk][jp & 1], srcl);
        const int hi = __shfl((int)pk[2 * kk + 1][jp & 1], srcl);
        W4[jp] = (lg >> 1) ? (unsigned)hi : (unsigned)lo;
      }
      uint4 wu; wu.x = W4[0]; wu.y = W4[1]; wu.z = W4[2]; wu.w = W4[3];
      const short8 pa = __builtin_bit_cast(short8, wu);
#pragma unroll
      for (int nt = 0; nt < 2; ++nt) {
        const short8 vb =
            *(const short8*)(vt + (nt * 16 + lr) * 74 + kk * 32 + lg * 8);
        oacc[nt] =
            __builtin_amdgcn_mfma_f32_16x16x32_bf16(pa, vb, oacc[nt], 0, 0, 0);
      }
    }

    // O -> Obuf (wave-local rows)
#pragma unroll
    for (int nt = 0; nt < 2; ++nt)
#pragma unroll
      for (int reg = 0; reg < 4; ++reg)
        Obuf[(w * 16 + lg * 4 + reg) * 392 + h * 32 + nt * 16 + lr] =
            f2b(oacc[nt][reg]);
  }

  // ================= proj: C[64][384] = Obuf @ wproj^T =================
  ushort8 bst[6];
  auto load_proj = [&](int s) {
    const int nh_ = s / 6, kch_ = s % 6;
#pragma unroll
    for (int i = 0; i < 6; ++i) {
      const int g = w * 6 + i;
      const int r = g * 8 + (lane >> 3);
      const int c = (lane & 7) ^ (r & 7);
      bst[i] = *(const ushort8*)(wproj + (size_t)(nh_ * 192 + r) * 384 +
                                 kch_ * 64 + c * 8);
    }
  };
  load_proj(0);

  floatx4 pacc[12];
#pragma unroll
  for (int nh = 0; nh < 2; ++nh) {       // n0 = nh*192
#pragma unroll
    for (int i = 0; i < 12; ++i) pacc[i] = (floatx4)0.f;
    for (int kch = 0; kch < 6; ++kch) {  // k0 = kch*64
      const int s = nh * 6 + kch;
      __syncthreads();                   // prev Bst/vt readers done
#pragma unroll
      for (int i = 0; i < 6; ++i)
        *(ushort8*)(Bst + (size_t)(w * 6 + i) * 512 + lane * 8) = bst[i];
      __syncthreads();
      // T14 fixed placement: prefetch next chunk after the barrier
      if (s + 1 < 12) load_proj(s + 1);
#pragma unroll
      for (int kh = 0; kh < 2; ++kh) {
        const short8 af = *(const short8*)(Obuf + (w * 16 + lr) * 392 +
                                           kch * 64 + kh * 32 + lg * 8);
#pragma unroll
        for (int nc = 0; nc < 12; ++nc) {
          const int nr = nc * 16 + lr;
          const short8 bf =
              *(const short8*)(Bst + nr * 64 + (((kh * 4 + lg) ^ (nr & 7)) * 8));
          pacc[nc] =
              __builtin_amdgcn_mfma_f32_16x16x32_bf16(af, bf, pacc[nc], 0, 0, 0);
        }
      }
    }
    // epilogue: rows w*16+lg*4+reg, cols nh*192 + nc*16 + lr
#pragma unroll
    for (int nc = 0; nc < 12; ++nc) {
      const int n = nh * 192 + nc * 16 + lr;
      const float bias = b_proj[n];
#pragma unroll
      for (int reg = 0; reg < 4; ++reg) {
        const int row = w * 16 + lg * 4 + reg;
        if (row < NTOK) {
          float* dst = (row >= P)
              ? x_out + ((size_t)(b * NWTOK + row - P)) * 384 + n
              : pbuf + ((size_t)(b * P + row)) * 384 + n;
          *dst = pacc[nc][reg] + bias;
        }
      }
    }
  }
}

// ---------------------------------------------------------------------------
// prompts_out = mean over 64 windows
// ---------------------------------------------------------------------------
__global__ __launch_bounds__(256) void reduce_prompts_kernel(
    const float* __restrict__ pbuf, float* __restrict__ po) {
  const int o = blockIdx.x * 256 + threadIdx.x;  // < 32*10*384
  const int b0 = o / 3840;
  const int rem = o - b0 * 3840;
  const float* base = pbuf + (size_t)b0 * 64 * 3840 + rem;
  float s = 0.f;
#pragma unroll 8
  for (int w = 0; w < 64; ++w) s += base[(size_t)w * 3840];
  po[o] = s * (1.f / 64.f);
}

extern "C" void kernel_launch(void* const* d_in, const int* in_sizes, int n_in,
                              void* d_out, int out_size, void* d_ws, size_t ws_size,
                              hipStream_t stream) {
  const float* x          = (const float*)d_in[0];
  const float* spa        = (const float*)d_in[1];
  const float* mask       = (const float*)d_in[2];
  const float* bias_table = (const float*)d_in[3];
  const float* w_qkv      = (const float*)d_in[4];
  const float* b_qkv      = (const float*)d_in[5];
  const float* w_proj     = (const float*)d_in[6];
  const float* b_proj     = (const float*)d_in[7];
  float* out = (float*)d_out;

  // ws layout (bytes):
  // [0, 77070336)            x_bf  (bf16 100352x384)  (consumed by gemm_qkv)
  // [77070336, 77316096)     xp_bf (bf16 320x384)
  // [77316096, 78200832)     wqkv_bf
  // [92798976, 324009984)    qkx (bf16 [2048][3][49][384])
  // [324009984, 324747264)   qkp (bf16 [32][3][10][384])
  // [324747264, 325042176)   wproj_bf
  // [325042176, 356499456)   pbuf  (f32 2048*10*384)
  // [356499456, 369082368)   combo (f32 [64][12][64][64])
  unsigned short* x_bf     = (unsigned short*)d_ws;
  unsigned short* xp_bf    = (unsigned short*)((char*)d_ws + 77070336ULL);
  unsigned short* wqkv_bf  = (unsigned short*)((char*)d_ws + 77316096ULL);
  unsigned short* qkx      = (unsigned short*)((char*)d_ws + 92798976ULL);
  unsigned short* qkp      = (unsigned short*)((char*)d_ws + 324009984ULL);
  unsigned short* wproj_bf = (unsigned short*)((char*)d_ws + 324747264ULL);
  float*          pbuf     = (float*)((char*)d_ws + 325042176ULL);
  float*          combo    = (float*)((char*)d_ws + 356499456ULL);

  convert_all_kernel<<<19164, 256, 0, stream>>>(x, spa, w_qkv, w_proj,
                                                x_bf, xp_bf, wqkv_bf, wproj_bf);
  combo_kernel<<<768, 256, 0, stream>>>(mask, bias_table, combo);
  gemm_qkv_kernel<<<9 * 787, 256, 0, stream>>>(x_bf, xp_bf, wqkv_bf, b_qkv,
                                               qkx, qkp);
  attn_proj_kernel<<<2048, 256, 0, stream>>>(qkx, qkp, combo, wproj_bf, b_proj,
                                             out + AW_OFF, out, pbuf);
  reduce_prompts_kernel<<<480, 256, 0, stream>>>(pbuf, out + PO_OFF);
}

// Round 15
// 586.691 us; speedup vs baseline: 1.1995x; 1.0031x over previous
//
#include <hip/hip_runtime.h>
#include <hip/hip_bf16.h>

#define P     10
#define NTOK  59
#define HEADS 12
#define NWTOK 49

#define AW_OFF 38535168   // frozen: verified by 12 passing rounds
#define PO_OFF 124096512  // frozen: verified by 12 passing rounds

typedef __attribute__((ext_vector_type(8))) short short8;
typedef __attribute__((ext_vector_type(8))) unsigned short ushort8;
typedef __attribute__((ext_vector_type(4))) float floatx4;
typedef float f4u __attribute__((ext_vector_type(4), aligned(4)));
typedef unsigned int uint_g __attribute__((address_space(1)));
typedef unsigned int uint_l __attribute__((address_space(3)));

__device__ __forceinline__ unsigned short f2b(float f) {
  unsigned u = __builtin_bit_cast(unsigned, f);
  u += 0x7fffu + ((u >> 16) & 1u);
  return (unsigned short)(u >> 16);
}

__device__ __forceinline__ void gll16(const void* g, void* l) {
  __builtin_amdgcn_global_load_lds((const uint_g*)g, (uint_l*)l, 16, 0, 0);
}

// bijective XCD-aware block swizzle (m204 form)
__device__ __forceinline__ int xcd_swz(int bid, int nwg) {
  const int q = nwg >> 3, r = nwg & 7;
  const int xcd = bid & 7, ord = bid >> 3;
  return (xcd < r ? xcd * (q + 1) : r * (q + 1) + (xcd - r) * q) + ord;
}

// ---------------------------------------------------------------------------
// merged convert f32 -> bf16: x | spa | w_qkv | w_proj in one launch
// ---------------------------------------------------------------------------
__global__ __launch_bounds__(256) void convert_all_kernel(
    const float* __restrict__ x, const float* __restrict__ spa,
    const float* __restrict__ wq, const float* __restrict__ wp,
    unsigned short* __restrict__ xb, unsigned short* __restrict__ xpb,
    unsigned short* __restrict__ wqb, unsigned short* __restrict__ wpb) {
  const int bid = blockIdx.x;
  const float* src; unsigned short* dst; int base;
  if (bid < 18816)      { src = x;   dst = xb;  base = bid; }
  else if (bid < 18876) { src = spa; dst = xpb; base = bid - 18816; }
  else if (bid < 19092) { src = wq;  dst = wqb; base = bid - 18876; }
  else                  { src = wp;  dst = wpb; base = bid - 19092; }
  const int i = (base * 256 + threadIdx.x) * 8;
  const float4 a = *(const float4*)(src + i);
  const float4 b = *(const float4*)(src + i + 4);
  ushort8 o;
  o[0] = f2b(a.x); o[1] = f2b(a.y); o[2] = f2b(a.z); o[3] = f2b(a.w);
  o[4] = f2b(b.x); o[5] = f2b(b.y); o[6] = f2b(b.z); o[7] = f2b(b.w);
  *(ushort8*)(dst + i) = o;
}

// ---------------------------------------------------------------------------
// combo[wnd][h][64][64]: padded with zeros outside the 49x49 valid region.
// ---------------------------------------------------------------------------
__global__ __launch_bounds__(256) void combo_kernel(
    const float* __restrict__ mask, const float* __restrict__ bias_table,
    float* __restrict__ combo) {
  const int bid = blockIdx.x;          // wnd*12 + h
  const int h = bid % HEADS, wnd = bid / HEADS;
#pragma unroll
  for (int e0 = 0; e0 < 4096; e0 += 256) {
    const int e = e0 + threadIdx.x;
    const int ti = e >> 6, tj = e & 63;
    float v = 0.f;
    if (ti >= P && ti < NTOK && tj >= P && tj < NTOK) {
      const int a = ti - P, c = tj - P;
      const int ai = a / 7, aj = a - ai * 7;
      const int bi = c / 7, bj = c - bi * 7;
      const int ridx = (ai - bi + 6) * 13 + (aj - bj + 6);
      v = bias_table[ridx * HEADS + h] + mask[((size_t)wnd * 49 + a) * 49 + c];
    }
    combo[((size_t)bid << 12) + e] = v;
  }
}

// ---------------------------------------------------------------------------
// QKV GEMM (proven R8-R11 form): A/B via global_load_lds, bf16 inputs.
// Output row-contiguous qkx[bb][sec][tok49][384], qkp[b0][sec][tok10][384].
// ---------------------------------------------------------------------------
__global__ __launch_bounds__(256) void gemm_qkv_kernel(
    const unsigned short* __restrict__ xb, const unsigned short* __restrict__ xp,
    const unsigned short* __restrict__ Bw, const float* __restrict__ b_qkv,
    unsigned short* __restrict__ qkx, unsigned short* __restrict__ qkp) {
  __shared__ unsigned short sbuf[18432];   // Asw|Bsw, reused as repack
  unsigned short* Asw = sbuf;
  unsigned short* Bsw = sbuf + 8192;
  const int t = threadIdx.x;
  const int w = t >> 6, lane = t & 63;
  const int lr = lane & 15, lg = lane >> 4;
  const int w0 = w >> 1, w1 = w & 1;
  const int wg = xcd_swz(blockIdx.x, 9 * 787);
  const int cb = wg % 9;          // column block 0..8
  const int my = wg / 9;          // row block 0..786
  const bool isP = my >= 784;
  const int n0 = cb * 128;
  const int srow = lane >> 3, cpos = lane & 7;

  floatx4 acc[4][4];
#pragma unroll
  for (int mr = 0; mr < 4; ++mr)
#pragma unroll
    for (int nc = 0; nc < 4; ++nc) acc[mr][nc] = (floatx4)0.f;

  for (int k0 = 0; k0 < 384; k0 += 64) {
#pragma unroll
    for (int i = 0; i < 4; ++i) {
      const int r = (w * 4 + i) * 8 + srow;
      const int c = cpos ^ (r & 7);
      const unsigned short* asrc;
      if (!isP) {
        asrc = xb + (size_t)(my * 128 + r) * 384 + k0 + c * 8;
      } else {
        int mp = (my - 784) * 128 + r;
        if (mp > 319) mp = 319;
        asrc = xp + (size_t)mp * 384 + k0 + c * 8;
      }
      gll16(asrc, Asw + (w * 4 + i) * 512);
      gll16(Bw + (size_t)(n0 + r) * 384 + k0 + c * 8, Bsw + (w * 4 + i) * 512);
    }
    __syncthreads();
#pragma unroll
    for (int kh = 0; kh < 2; ++kh) {
      short8 af[4], bf[4];
#pragma unroll
      for (int mr = 0; mr < 4; ++mr) {
        const int r = w0 * 64 + mr * 16 + lr;
        af[mr] = *(const short8*)(Asw + r * 64 + (((kh * 4 + lg) ^ (r & 7)) * 8));
      }
#pragma unroll
      for (int nc = 0; nc < 4; ++nc) {
        const int r = w1 * 64 + nc * 16 + lr;
        bf[nc] = *(const short8*)(Bsw + r * 64 + (((kh * 4 + lg) ^ (r & 7)) * 8));
      }
#pragma unroll
      for (int mr = 0; mr < 4; ++mr)
#pragma unroll
        for (int nc = 0; nc < 4; ++nc)
          acc[mr][nc] = __builtin_amdgcn_mfma_f32_16x16x32_bf16(
              af[mr], bf[nc], acc[mr][nc], 0, 0, 0);
    }
    __syncthreads();
  }

  // ---- epilogue: +bias, per-wave 64x64 LDS repack, 128B/lane stores ----
  const int sec = cb / 3;
  const int nis = (cb - sec * 3) * 128;
  float bias[4];
#pragma unroll
  for (int nc = 0; nc < 4; ++nc)
    bias[nc] = b_qkv[n0 + w1 * 64 + nc * 16 + lr];

  unsigned short* rp = sbuf + w * 4608;   // own wave: [64][72]
#pragma unroll
  for (int mr = 0; mr < 4; ++mr)
#pragma unroll
    for (int nc = 0; nc < 4; ++nc)
#pragma unroll
      for (int reg = 0; reg < 4; ++reg)
        rp[(mr * 16 + lg * 4 + reg) * 72 + nc * 16 + lr] =
            f2b(acc[mr][nc][reg] + bias[nc]);
  __syncthreads();

  const int rr = lane;
  unsigned short* dst = nullptr;
  if (!isP) {
    const int m = my * 128 + w0 * 64 + rr;
    const int bb = m / 49, tok = m - bb * 49;
    dst = qkx + ((size_t)(bb * 3 + sec) * 49 + tok) * 384 + nis + w1 * 64;
  } else {
    const int mp = (my - 784) * 128 + w0 * 64 + rr;
    if (mp < 320) {
      const int b0 = mp / 10, ptok = mp - b0 * 10;
      dst = qkp + ((size_t)(b0 * 3 + sec) * 10 + ptok) * 384 + nis + w1 * 64;
    }
  }
  if (dst) {
#pragma unroll
    for (int u = 0; u < 8; ++u)
      *(ushort8*)(dst + u * 8) = *(const ushort8*)(rp + rr * 72 + u * 8);
  }
}

// ---------------------------------------------------------------------------
// FUSED attention + proj (R11 structure). 2048 blocks, 4 waves, LDS 74752.
// T14 FIX: prefetches issued AFTER the post-staging barrier, so the
// compiler's vmcnt(0)-before-s_barrier drain no longer kills the overlap.
// ---------------------------------------------------------------------------
__global__ __launch_bounds__(256) void attn_proj_kernel(
    const unsigned short* __restrict__ qkx, const unsigned short* __restrict__ qkp,
    const float* __restrict__ combo, const unsigned short* __restrict__ wproj,
    const float* __restrict__ b_proj, float* __restrict__ aw_out,
    float* __restrict__ x_out, float* __restrict__ pbuf) {
  __shared__ char lds[74752];
  unsigned short* Obuf = (unsigned short*)lds;             // [64][392] bf16
  unsigned short* qs   = (unsigned short*)(lds + 50176);   // [64][40]
  unsigned short* ks   = (unsigned short*)(lds + 55296);   // [64][40]
  unsigned short* vt   = (unsigned short*)(lds + 60416);   // [32][74] V^T
  unsigned short* Bst  = (unsigned short*)(lds + 50176);   // proj: [192][64]

  const int b = blockIdx.x;
  const int t = threadIdx.x;
  const int w = t >> 6, lane = t & 63, lr = lane & 15, lg = lane >> 4;
  const float scale = 0.17677669529663687f;
  const int q = w * 16 + lr;

  // staging registers (T14: issue-early / write-late)
  ushort8 nq, nk, nv;
  const int srow_ = t >> 2, sdc = (t & 3) * 8;
  auto load_head = [&](int h) {
    if (t < 236) {
      if (srow_ < P) {
        const unsigned short* pb =
            qkp + ((size_t)((b >> 6) * 3) * 10 + srow_) * 384 + h * 32 + sdc;
        nq = *(const ushort8*)(pb);
        nk = *(const ushort8*)(pb + 10 * 384);
        nv = *(const ushort8*)(pb + 20 * 384);
      } else {
        const unsigned short* xbp =
            qkx + ((size_t)(b * 3) * 49 + (srow_ - P)) * 384 + h * 32 + sdc;
        nq = *(const ushort8*)(xbp);
        nk = *(const ushort8*)(xbp + 49 * 384);
        nv = *(const ushort8*)(xbp + 98 * 384);
      }
    }
  };

  // prologue: zero vt pad cols (persist across heads), load head 0
  if (t < 160) vt[(t / 5) * 74 + 59 + (t % 5)] = 0;
  load_head(0);

  // ================= attention: 12 head rounds =================
  for (int h = 0; h < HEADS; ++h) {
    __syncthreads();   // staging region free (prev round's PV reads done)
    if (t < 236) {
      *(ushort8*)(qs + srow_ * 40 + sdc) = nq;
      *(ushort8*)(ks + srow_ * 40 + sdc) = nk;
#pragma unroll
      for (int j = 0; j < 8; ++j) vt[(sdc + j) * 74 + srow_] = nv[j];
    }
    __syncthreads();
    // T14 fixed placement: issue AFTER the barrier so the drain-before-
    // s_barrier doesn't serialize the prefetch; nq/nk/nv are dead here.
    if (h + 1 < HEADS) load_head(h + 1);

    // swapped QK^T: lane holds S[q][kk]
    const short8 qa = *(const short8*)(qs + q * 40 + lg * 8);
    floatx4 sacc[4];
#pragma unroll
    for (int nt = 0; nt < 4; ++nt) {
      const short8 kb = *(const short8*)(ks + (nt * 16 + lr) * 40 + lg * 8);
      sacc[nt] =
          __builtin_amdgcn_mfma_f32_16x16x32_bf16(kb, qa, (floatx4)0.f, 0, 0, 0);
    }

    // raw S straight from registers
    if (q < NTOK) {
      float* rowp = aw_out + ((size_t)(b * HEADS + h)) * 3481 + q * 59;
#pragma unroll
      for (int nt = 0; nt < 3; ++nt)
        *(f4u*)(rowp + nt * 16 + lg * 4) = __builtin_bit_cast(f4u, sacc[nt]);
      if (lg < 2) {
        *(f4u*)(rowp + 48 + lg * 4) = __builtin_bit_cast(f4u, sacc[3]);
      } else if (lg == 2) {
        rowp[56] = sacc[3][0]; rowp[57] = sacc[3][1]; rowp[58] = sacc[3][2];
      }
    }

    // in-register softmax
    const float* comb =
        combo + (((size_t)((b & 63) * HEADS + h)) << 12) + q * 64;
    float ev[4][4];
    float mx = -3.0e38f;
#pragma unroll
    for (int nt = 0; nt < 4; ++nt) {
      const float4 c4 = *(const float4*)(comb + nt * 16 + lg * 4);
      const float cc[4] = {c4.x, c4.y, c4.z, c4.w};
#pragma unroll
      for (int reg = 0; reg < 4; ++reg) {
        const int kk2 = nt * 16 + lg * 4 + reg;
        const float v = (q < NTOK && kk2 < NTOK)
                            ? fmaf(sacc[nt][reg], scale, cc[reg])
                            : -3.0e38f;
        ev[nt][reg] = v;
        mx = fmaxf(mx, v);
      }
    }
    mx = fmaxf(mx, __shfl_xor(mx, 16));
    mx = fmaxf(mx, __shfl_xor(mx, 32));
    float sm = 0.f;
#pragma unroll
    for (int nt = 0; nt < 4; ++nt)
#pragma unroll
      for (int reg = 0; reg < 4; ++reg) {
        const float e = __expf(ev[nt][reg] - mx);
        ev[nt][reg] = e;
        sm += e;
      }
    sm += __shfl_xor(sm, 16);
    sm += __shfl_xor(sm, 32);
    const float inv = 1.0f / sm;

    // pack P pairs: pk[nt][pp] = P[q][nt*16+lg*4+2pp..+1]
    unsigned pk[4][2];
#pragma unroll
    for (int nt = 0; nt < 4; ++nt)
#pragma unroll
      for (int pp = 0; pp < 2; ++pp)
        pk[nt][pp] = (unsigned)f2b(ev[nt][2 * pp] * inv) |
                     ((unsigned)f2b(ev[nt][2 * pp + 1] * inv) << 16);

    // shfl redistribution to MFMA A-layout, then PV
    floatx4 oacc[2];
    oacc[0] = (floatx4)0.f; oacc[1] = (floatx4)0.f;
#pragma unroll
    for (int kk = 0; kk < 2; ++kk) {
      unsigned W4[4];
#pragma unroll
      for (int jp = 0; jp < 4; ++jp) {
        const int srcl = lr + 16 * (2 * (lg & 1) + (jp >> 1));
        const int lo = __shfl((int)pk[2 * kk][jp & 1], srcl);
        const int hi = __shfl((int)pk[2 * kk + 1][jp & 1], srcl);
        W4[jp] = (lg >> 1) ? (unsigned)hi : (unsigned)lo;
      }
      uint4 wu; wu.x = W4[0]; wu.y = W4[1]; wu.z = W4[2]; wu.w = W4[3];
      const short8 pa = __builtin_bit_cast(short8, wu);
#pragma unroll
      for (int nt = 0; nt < 2; ++nt) {
        const short8 vb =
            *(const short8*)(vt + (nt * 16 + lr) * 74 + kk * 32 + lg * 8);
        oacc[nt] =
            __builtin_amdgcn_mfma_f32_16x16x32_bf16(pa, vb, oacc[nt], 0, 0, 0);
      }
    }

    // O -> Obuf (wave-local rows)
#pragma unroll
    for (int nt = 0; nt < 2; ++nt)
#pragma unroll
      for (int reg = 0; reg < 4; ++reg)
        Obuf[(w * 16 + lg * 4 + reg) * 392 + h * 32 + nt * 16 + lr] =
            f2b(oacc[nt][reg]);
  }

  // ================= proj: C[64][384] = Obuf @ wproj^T =================
  ushort8 bst[6];
  auto load_proj = [&](int s) {
    const int nh_ = s / 6, kch_ = s % 6;
#pragma unroll
    for (int i = 0; i < 6; ++i) {
      const int g = w * 6 + i;
      const int r = g * 8 + (lane >> 3);
      const int c = (lane & 7) ^ (r & 7);
      bst[i] = *(const ushort8*)(wproj + (size_t)(nh_ * 192 + r) * 384 +
                                 kch_ * 64 + c * 8);
    }
  };
  load_proj(0);

  floatx4 pacc[12];
#pragma unroll
  for (int nh = 0; nh < 2; ++nh) {       // n0 = nh*192
#pragma unroll
    for (int i = 0; i < 12; ++i) pacc[i] = (floatx4)0.f;
    for (int kch = 0; kch < 6; ++kch) {  // k0 = kch*64
      const int s = nh * 6 + kch;
      __syncthreads();                   // prev Bst/vt readers done
#pragma unroll
      for (int i = 0; i < 6; ++i)
        *(ushort8*)(Bst + (size_t)(w * 6 + i) * 512 + lane * 8) = bst[i];
      __syncthreads();
      // T14 fixed placement: prefetch next chunk after the barrier
      if (s + 1 < 12) load_proj(s + 1);
#pragma unroll
      for (int kh = 0; kh < 2; ++kh) {
        const short8 af = *(const short8*)(Obuf + (w * 16 + lr) * 392 +
                                           kch * 64 + kh * 32 + lg * 8);
#pragma unroll
        for (int nc = 0; nc < 12; ++nc) {
          const int nr = nc * 16 + lr;
          const short8 bf =
              *(const short8*)(Bst + nr * 64 + (((kh * 4 + lg) ^ (nr & 7)) * 8));
          pacc[nc] =
              __builtin_amdgcn_mfma_f32_16x16x32_bf16(af, bf, pacc[nc], 0, 0, 0);
        }
      }
    }
    // epilogue: rows w*16+lg*4+reg, cols nh*192 + nc*16 + lr
#pragma unroll
    for (int nc = 0; nc < 12; ++nc) {
      const int n = nh * 192 + nc * 16 + lr;
      const float bias = b_proj[n];
#pragma unroll
      for (int reg = 0; reg < 4; ++reg) {
        const int row = w * 16 + lg * 4 + reg;
        if (row < NTOK) {
          float* dst = (row >= P)
              ? x_out + ((size_t)(b * NWTOK + row - P)) * 384 + n
              : pbuf + ((size_t)(b * P + row)) * 384 + n;
          *dst = pacc[nc][reg] + bias;
        }
      }
    }
  }
}

// ---------------------------------------------------------------------------
// prompts_out = mean over 64 windows
// ---------------------------------------------------------------------------
__global__ __launch_bounds__(256) void reduce_prompts_kernel(
    const float* __restrict__ pbuf, float* __restrict__ po) {
  const int o = blockIdx.x * 256 + threadIdx.x;  // < 32*10*384
  const int b0 = o / 3840;
  const int rem = o - b0 * 3840;
  const float* base = pbuf + (size_t)b0 * 64 * 3840 + rem;
  float s = 0.f;
#pragma unroll 8
  for (int w = 0; w < 64; ++w) s += base[(size_t)w * 3840];
  po[o] = s * (1.f / 64.f);
}

extern "C" void kernel_launch(void* const* d_in, const int* in_sizes, int n_in,
                              void* d_out, int out_size, void* d_ws, size_t ws_size,
                              hipStream_t stream) {
  const float* x          = (const float*)d_in[0];
  const float* spa        = (const float*)d_in[1];
  const float* mask       = (const float*)d_in[2];
  const float* bias_table = (const float*)d_in[3];
  const float* w_qkv      = (const float*)d_in[4];
  const float* b_qkv      = (const float*)d_in[5];
  const float* w_proj     = (const float*)d_in[6];
  const float* b_proj     = (const float*)d_in[7];
  float* out = (float*)d_out;

  // ws layout (bytes):
  // [0, 77070336)            x_bf  (bf16 100352x384)  (consumed by gemm_qkv)
  // [77070336, 77316096)     xp_bf (bf16 320x384)
  // [77316096, 78200832)     wqkv_bf
  // [92798976, 324009984)    qkx (bf16 [2048][3][49][384])
  // [324009984, 324747264)   qkp (bf16 [32][3][10][384])
  // [324747264, 325042176)   wproj_bf
  // [325042176, 356499456)   pbuf  (f32 2048*10*384)
  // [356499456, 369082368)   combo (f32 [64][12][64][64])
  unsigned short* x_bf     = (unsigned short*)d_ws;
  unsigned short* xp_bf    = (unsigned short*)((char*)d_ws + 77070336ULL);
  unsigned short* wqkv_bf  = (unsigned short*)((char*)d_ws + 77316096ULL);
  unsigned short* qkx      = (unsigned short*)((char*)d_ws + 92798976ULL);
  unsigned short* qkp      = (unsigned short*)((char*)d_ws + 324009984ULL);
  unsigned short* wproj_bf = (unsigned short*)((char*)d_ws + 324747264ULL);
  float*          pbuf     = (float*)((char*)d_ws + 325042176ULL);
  float*          combo    = (float*)((char*)d_ws + 356499456ULL);

  convert_all_kernel<<<19164, 256, 0, stream>>>(x, spa, w_qkv, w_proj,
                                                x_bf, xp_bf, wqkv_bf, wproj_bf);
  combo_kernel<<<768, 256, 0, stream>>>(mask, bias_table, combo);
  gemm_qkv_kernel<<<9 * 787, 256, 0, stream>>>(x_bf, xp_bf, wqkv_bf, b_qkv,
                                               qkx, qkp);
  attn_proj_kernel<<<2048, 256, 0, stream>>>(qkx, qkp, combo, wproj_bf, b_proj,
                                             out + AW_OFF, out, pbuf);
  reduce_prompts_kernel<<<480, 256, 0, stream>>>(pbuf, out + PO_OFF);
}

// Round 16
// 542.305 us; speedup vs baseline: 1.2977x; 1.0818x over previous
//
#include <hip/hip_runtime.h>
#include <hip/hip_bf16.h>

#define P     10
#define NTOK  59
#define HEADS 12
#define NWTOK 49

#define AW_OFF 38535168   // frozen: verified by 13 passing rounds
#define PO_OFF 124096512  // frozen: verified by 13 passing rounds

typedef __attribute__((ext_vector_type(8))) short short8;
typedef __attribute__((ext_vector_type(8))) unsigned short ushort8;
typedef __attribute__((ext_vector_type(4))) float floatx4;
typedef float f4u __attribute__((ext_vector_type(4), aligned(4)));
typedef unsigned int uint_g __attribute__((address_space(1)));
typedef unsigned int uint_l __attribute__((address_space(3)));

__device__ __forceinline__ unsigned short f2b(float f) {
  unsigned u = __builtin_bit_cast(unsigned, f);
  u += 0x7fffu + ((u >> 16) & 1u);
  return (unsigned short)(u >> 16);
}

__device__ __forceinline__ void gll16(const void* g, void* l) {
  __builtin_amdgcn_global_load_lds((const uint_g*)g, (uint_l*)l, 16, 0, 0);
}

// bijective XCD-aware block swizzle (m204 form)
__device__ __forceinline__ int xcd_swz(int bid, int nwg) {
  const int q = nwg >> 3, r = nwg & 7;
  const int xcd = bid & 7, ord = bid >> 3;
  return (xcd < r ? xcd * (q + 1) : r * (q + 1) + (xcd - r) * q) + ord;
}

// ---------------------------------------------------------------------------
// merged convert f32 -> bf16: x | spa | w_qkv | w_proj in one launch
// ---------------------------------------------------------------------------
__global__ __launch_bounds__(256) void convert_all_kernel(
    const float* __restrict__ x, const float* __restrict__ spa,
    const float* __restrict__ wq, const float* __restrict__ wp,
    unsigned short* __restrict__ xb, unsigned short* __restrict__ xpb,
    unsigned short* __restrict__ wqb, unsigned short* __restrict__ wpb) {
  const int bid = blockIdx.x;
  const float* src; unsigned short* dst; int base;
  if (bid < 18816)      { src = x;   dst = xb;  base = bid; }
  else if (bid < 18876) { src = spa; dst = xpb; base = bid - 18816; }
  else if (bid < 19092) { src = wq;  dst = wqb; base = bid - 18876; }
  else                  { src = wp;  dst = wpb; base = bid - 19092; }
  const int i = (base * 256 + threadIdx.x) * 8;
  const float4 a = *(const float4*)(src + i);
  const float4 b = *(const float4*)(src + i + 4);
  ushort8 o;
  o[0] = f2b(a.x); o[1] = f2b(a.y); o[2] = f2b(a.z); o[3] = f2b(a.w);
  o[4] = f2b(b.x); o[5] = f2b(b.y); o[6] = f2b(b.z); o[7] = f2b(b.w);
  *(ushort8*)(dst + i) = o;
}

// ---------------------------------------------------------------------------
// combo[wnd][h][64][64]: padded with zeros outside the 49x49 valid region.
// ---------------------------------------------------------------------------
__global__ __launch_bounds__(256) void combo_kernel(
    const float* __restrict__ mask, const float* __restrict__ bias_table,
    float* __restrict__ combo) {
  const int bid = blockIdx.x;          // wnd*12 + h
  const int h = bid % HEADS, wnd = bid / HEADS;
#pragma unroll
  for (int e0 = 0; e0 < 4096; e0 += 256) {
    const int e = e0 + threadIdx.x;
    const int ti = e >> 6, tj = e & 63;
    float v = 0.f;
    if (ti >= P && ti < NTOK && tj >= P && tj < NTOK) {
      const int a = ti - P, c = tj - P;
      const int ai = a / 7, aj = a - ai * 7;
      const int bi = c / 7, bj = c - bi * 7;
      const int ridx = (ai - bi + 6) * 13 + (aj - bj + 6);
      v = bias_table[ridx * HEADS + h] + mask[((size_t)wnd * 49 + a) * 49 + c];
    }
    combo[((size_t)bid << 12) + e] = v;
  }
}

// ---------------------------------------------------------------------------
// QKV GEMM (proven R8-R15 form): A/B via global_load_lds, bf16 inputs.
// Output row-contiguous qkx[bb][sec][tok49][384], qkp[b0][sec][tok10][384].
// ---------------------------------------------------------------------------
__global__ __launch_bounds__(256) void gemm_qkv_kernel(
    const unsigned short* __restrict__ xb, const unsigned short* __restrict__ xp,
    const unsigned short* __restrict__ Bw, const float* __restrict__ b_qkv,
    unsigned short* __restrict__ qkx, unsigned short* __restrict__ qkp) {
  __shared__ unsigned short sbuf[18432];   // Asw|Bsw, reused as repack
  unsigned short* Asw = sbuf;
  unsigned short* Bsw = sbuf + 8192;
  const int t = threadIdx.x;
  const int w = t >> 6, lane = t & 63;
  const int lr = lane & 15, lg = lane >> 4;
  const int w0 = w >> 1, w1 = w & 1;
  const int wg = xcd_swz(blockIdx.x, 9 * 787);
  const int cb = wg % 9;          // column block 0..8
  const int my = wg / 9;          // row block 0..786
  const bool isP = my >= 784;
  const int n0 = cb * 128;
  const int srow = lane >> 3, cpos = lane & 7;

  floatx4 acc[4][4];
#pragma unroll
  for (int mr = 0; mr < 4; ++mr)
#pragma unroll
    for (int nc = 0; nc < 4; ++nc) acc[mr][nc] = (floatx4)0.f;

  for (int k0 = 0; k0 < 384; k0 += 64) {
#pragma unroll
    for (int i = 0; i < 4; ++i) {
      const int r = (w * 4 + i) * 8 + srow;
      const int c = cpos ^ (r & 7);
      const unsigned short* asrc;
      if (!isP) {
        asrc = xb + (size_t)(my * 128 + r) * 384 + k0 + c * 8;
      } else {
        int mp = (my - 784) * 128 + r;
        if (mp > 319) mp = 319;
        asrc = xp + (size_t)mp * 384 + k0 + c * 8;
      }
      gll16(asrc, Asw + (w * 4 + i) * 512);
      gll16(Bw + (size_t)(n0 + r) * 384 + k0 + c * 8, Bsw + (w * 4 + i) * 512);
    }
    __syncthreads();
#pragma unroll
    for (int kh = 0; kh < 2; ++kh) {
      short8 af[4], bf[4];
#pragma unroll
      for (int mr = 0; mr < 4; ++mr) {
        const int r = w0 * 64 + mr * 16 + lr;
        af[mr] = *(const short8*)(Asw + r * 64 + (((kh * 4 + lg) ^ (r & 7)) * 8));
      }
#pragma unroll
      for (int nc = 0; nc < 4; ++nc) {
        const int r = w1 * 64 + nc * 16 + lr;
        bf[nc] = *(const short8*)(Bsw + r * 64 + (((kh * 4 + lg) ^ (r & 7)) * 8));
      }
#pragma unroll
      for (int mr = 0; mr < 4; ++mr)
#pragma unroll
        for (int nc = 0; nc < 4; ++nc)
          acc[mr][nc] = __builtin_amdgcn_mfma_f32_16x16x32_bf16(
              af[mr], bf[nc], acc[mr][nc], 0, 0, 0);
    }
    __syncthreads();
  }

  // ---- epilogue: +bias, per-wave 64x64 LDS repack, 128B/lane stores ----
  const int sec = cb / 3;
  const int nis = (cb - sec * 3) * 128;
  float bias[4];
#pragma unroll
  for (int nc = 0; nc < 4; ++nc)
    bias[nc] = b_qkv[n0 + w1 * 64 + nc * 16 + lr];

  unsigned short* rp = sbuf + w * 4608;   // own wave: [64][72]
#pragma unroll
  for (int mr = 0; mr < 4; ++mr)
#pragma unroll
    for (int nc = 0; nc < 4; ++nc)
#pragma unroll
      for (int reg = 0; reg < 4; ++reg)
        rp[(mr * 16 + lg * 4 + reg) * 72 + nc * 16 + lr] =
            f2b(acc[mr][nc][reg] + bias[nc]);
  __syncthreads();

  const int rr = lane;
  unsigned short* dst = nullptr;
  if (!isP) {
    const int m = my * 128 + w0 * 64 + rr;
    const int bb = m / 49, tok = m - bb * 49;
    dst = qkx + ((size_t)(bb * 3 + sec) * 49 + tok) * 384 + nis + w1 * 64;
  } else {
    const int mp = (my - 784) * 128 + w0 * 64 + rr;
    if (mp < 320) {
      const int b0 = mp / 10, ptok = mp - b0 * 10;
      dst = qkp + ((size_t)(b0 * 3 + sec) * 10 + ptok) * 384 + nis + w1 * 64;
    }
  }
  if (dst) {
#pragma unroll
    for (int u = 0; u < 8; ++u)
      *(ushort8*)(dst + u * 8) = *(const ushort8*)(rp + rr * 72 + u * 8);
  }
}

// ---------------------------------------------------------------------------
// FUSED attention + proj, 512 threads (8 waves), 2 heads per round.
// Waves 0-3 -> even head, waves 4-7 -> odd head; per-wave code identical to
// the verified R11 path. Proj: 8 waves = (row-group, n-subgroup), shared Bst.
// LDS 80128 B -> 2 blocks/CU = 16 waves/CU (2x R11 occupancy, same work).
// ---------------------------------------------------------------------------
__global__ __launch_bounds__(512, 4) void attn_proj_kernel(
    const unsigned short* __restrict__ qkx, const unsigned short* __restrict__ qkp,
    const float* __restrict__ combo, const unsigned short* __restrict__ wproj,
    const float* __restrict__ b_proj, float* __restrict__ aw_out,
    float* __restrict__ x_out, float* __restrict__ pbuf) {
  __shared__ char lds[80128];
  unsigned short* Obuf = (unsigned short*)lds;          // [64][392] bf16
  // staging: two head-slices at 50176 + g*14976: {qs[64][40], ks[64][40],
  //          vt[32][74]}; proj Bst [192][64] aliases the staging region.
  unsigned short* Bst = (unsigned short*)(lds + 50176);

  const int b = blockIdx.x;
  const int t = threadIdx.x;
  const int w = t >> 6, lane = t & 63, lr = lane & 15, lg = lane >> 4;
  const int hgrp = w >> 2;        // which head of the pair (compute side)
  const int wq = w & 3;           // q-row group
  const float scale = 0.17677669529663687f;
  const int q = wq * 16 + lr;

  unsigned short* qs = (unsigned short*)(lds + 50176 + hgrp * 14976);
  unsigned short* ks = (unsigned short*)(lds + 50176 + hgrp * 14976 + 5120);
  unsigned short* vt = (unsigned short*)(lds + 50176 + hgrp * 14976 + 10240);

  // staging thread mapping: threads 0-255 stage even head, 256-511 odd head
  const int tt = t & 255, sgrp = t >> 8;
  const int srow_ = tt >> 2, sdc = (tt & 3) * 8;
  unsigned short* qsS = (unsigned short*)(lds + 50176 + sgrp * 14976);
  unsigned short* ksS = qsS + 2560;   // +5120 B
  unsigned short* vtS = qsS + 5120;   // +10240 B

  ushort8 nq, nk, nv;
  auto load_head = [&](int rpair) {   // loads head 2*rpair + sgrp
    if (tt < 236) {
      const int h = rpair * 2 + sgrp;
      if (srow_ < P) {
        const unsigned short* pb =
            qkp + ((size_t)((b >> 6) * 3) * 10 + srow_) * 384 + h * 32 + sdc;
        nq = *(const ushort8*)(pb);
        nk = *(const ushort8*)(pb + 10 * 384);
        nv = *(const ushort8*)(pb + 20 * 384);
      } else {
        const unsigned short* xbp =
            qkx + ((size_t)(b * 3) * 49 + (srow_ - P)) * 384 + h * 32 + sdc;
        nq = *(const ushort8*)(xbp);
        nk = *(const ushort8*)(xbp + 49 * 384);
        nv = *(const ushort8*)(xbp + 98 * 384);
      }
    }
  };

  // prologue: zero vt pad cols for both head slices; load round-0 heads
  if (t < 320) {
    const int g2 = t / 160, e = t - g2 * 160;
    unsigned short* vtZ = (unsigned short*)(lds + 50176 + g2 * 14976 + 10240);
    vtZ[(e / 5) * 74 + 59 + (e % 5)] = 0;
  }
  load_head(0);

  // ================= attention: 6 rounds x 2 heads =================
  for (int r = 0; r < 6; ++r) {
    const int h = r * 2 + hgrp;
    __syncthreads();   // staging region free (prev round's reads done)
    if (tt < 236) {
      *(ushort8*)(qsS + srow_ * 40 + sdc) = nq;
      *(ushort8*)(ksS + srow_ * 40 + sdc) = nk;
#pragma unroll
      for (int j = 0; j < 8; ++j) vtS[(sdc + j) * 74 + srow_] = nv[j];
    }
    __syncthreads();
    if (r + 1 < 6) load_head(r + 1);   // rides under compute below

    // swapped QK^T: lane holds S[q][kk]
    const short8 qa = *(const short8*)(qs + q * 40 + lg * 8);
    floatx4 sacc[4];
#pragma unroll
    for (int nt = 0; nt < 4; ++nt) {
      const short8 kb = *(const short8*)(ks + (nt * 16 + lr) * 40 + lg * 8);
      sacc[nt] =
          __builtin_amdgcn_mfma_f32_16x16x32_bf16(kb, qa, (floatx4)0.f, 0, 0, 0);
    }

    // raw S straight from registers
    if (q < NTOK) {
      float* rowp = aw_out + ((size_t)(b * HEADS + h)) * 3481 + q * 59;
#pragma unroll
      for (int nt = 0; nt < 3; ++nt)
        *(f4u*)(rowp + nt * 16 + lg * 4) = __builtin_bit_cast(f4u, sacc[nt]);
      if (lg < 2) {
        *(f4u*)(rowp + 48 + lg * 4) = __builtin_bit_cast(f4u, sacc[3]);
      } else if (lg == 2) {
        rowp[56] = sacc[3][0]; rowp[57] = sacc[3][1]; rowp[58] = sacc[3][2];
      }
    }

    // in-register softmax
    const float* comb =
        combo + (((size_t)((b & 63) * HEADS + h)) << 12) + q * 64;
    float ev[4][4];
    float mx = -3.0e38f;
#pragma unroll
    for (int nt = 0; nt < 4; ++nt) {
      const float4 c4 = *(const float4*)(comb + nt * 16 + lg * 4);
      const float cc[4] = {c4.x, c4.y, c4.z, c4.w};
#pragma unroll
      for (int reg = 0; reg < 4; ++reg) {
        const int kk2 = nt * 16 + lg * 4 + reg;
        const float v = (q < NTOK && kk2 < NTOK)
                            ? fmaf(sacc[nt][reg], scale, cc[reg])
                            : -3.0e38f;
        ev[nt][reg] = v;
        mx = fmaxf(mx, v);
      }
    }
    mx = fmaxf(mx, __shfl_xor(mx, 16));
    mx = fmaxf(mx, __shfl_xor(mx, 32));
    float sm = 0.f;
#pragma unroll
    for (int nt = 0; nt < 4; ++nt)
#pragma unroll
      for (int reg = 0; reg < 4; ++reg) {
        const float e = __expf(ev[nt][reg] - mx);
        ev[nt][reg] = e;
        sm += e;
      }
    sm += __shfl_xor(sm, 16);
    sm += __shfl_xor(sm, 32);
    const float inv = 1.0f / sm;

    // pack P pairs
    unsigned pk[4][2];
#pragma unroll
    for (int nt = 0; nt < 4; ++nt)
#pragma unroll
      for (int pp = 0; pp < 2; ++pp)
        pk[nt][pp] = (unsigned)f2b(ev[nt][2 * pp] * inv) |
                     ((unsigned)f2b(ev[nt][2 * pp + 1] * inv) << 16);

    // shfl redistribution to MFMA A-layout, then PV
    floatx4 oacc[2];
    oacc[0] = (floatx4)0.f; oacc[1] = (floatx4)0.f;
#pragma unroll
    for (int kk = 0; kk < 2; ++kk) {
      unsigned W4[4];
#pragma unroll
      for (int jp = 0; jp < 4; ++jp) {
        const int srcl = lr + 16 * (2 * (lg & 1) + (jp >> 1));
        const int lo = __shfl((int)pk[2 * kk][jp & 1], srcl);
        const int hi = __shfl((int)pk[2 * kk + 1][jp & 1], srcl);
        W4[jp] = (lg >> 1) ? (unsigned)hi : (unsigned)lo;
      }
      uint4 wu; wu.x = W4[0]; wu.y = W4[1]; wu.z = W4[2]; wu.w = W4[3];
      const short8 pa = __builtin_bit_cast(short8, wu);
#pragma unroll
      for (int nt = 0; nt < 2; ++nt) {
        const short8 vb =
            *(const short8*)(vt + (nt * 16 + lr) * 74 + kk * 32 + lg * 8);
        oacc[nt] =
            __builtin_amdgcn_mfma_f32_16x16x32_bf16(pa, vb, oacc[nt], 0, 0, 0);
      }
    }

    // O -> Obuf (disjoint cols per head group)
#pragma unroll
    for (int nt = 0; nt < 2; ++nt)
#pragma unroll
      for (int reg = 0; reg < 4; ++reg)
        Obuf[(wq * 16 + lg * 4 + reg) * 392 + h * 32 + nt * 16 + lr] =
            f2b(oacc[nt][reg]);
  }

  // ================= proj: C[64][384] = Obuf @ wproj^T =================
  // 8 waves: row-group rw = w&3, n-subgroup ng = w>>2 (96 cols each).
  const int rw = w & 3, ng = w >> 2;
  ushort8 bst[3];
  auto load_proj = [&](int s) {
    const int nh_ = s / 6, kch_ = s % 6;
#pragma unroll
    for (int i = 0; i < 3; ++i) {
      const int g = w * 3 + i;               // 0..23
      const int r = g * 8 + (lane >> 3);     // 0..191
      const int c = (lane & 7) ^ (r & 7);
      bst[i] = *(const ushort8*)(wproj + (size_t)(nh_ * 192 + r) * 384 +
                                 kch_ * 64 + c * 8);
    }
  };
  load_proj(0);

  floatx4 pacc[6];
#pragma unroll
  for (int nh = 0; nh < 2; ++nh) {       // n0 = nh*192
#pragma unroll
    for (int i = 0; i < 6; ++i) pacc[i] = (floatx4)0.f;
    for (int kch = 0; kch < 6; ++kch) {  // k0 = kch*64
      const int s = nh * 6 + kch;
      __syncthreads();                   // prev Bst/vt readers done
#pragma unroll
      for (int i = 0; i < 3; ++i)
        *(ushort8*)(Bst + (size_t)(w * 3 + i) * 512 + lane * 8) = bst[i];
      __syncthreads();
      if (s + 1 < 12) load_proj(s + 1);  // rides under MFMA below
#pragma unroll
      for (int kh = 0; kh < 2; ++kh) {
        const short8 af = *(const short8*)(Obuf + (rw * 16 + lr) * 392 +
                                           kch * 64 + kh * 32 + lg * 8);
#pragma unroll
        for (int nc = 0; nc < 6; ++nc) {
          const int nr = ng * 96 + nc * 16 + lr;
          const short8 bf =
              *(const short8*)(Bst + nr * 64 + (((kh * 4 + lg) ^ (nr & 7)) * 8));
          pacc[nc] =
              __builtin_amdgcn_mfma_f32_16x16x32_bf16(af, bf, pacc[nc], 0, 0, 0);
        }
      }
    }
    // epilogue: rows rw*16+lg*4+reg, cols nh*192 + ng*96 + nc*16 + lr
#pragma unroll
    for (int nc = 0; nc < 6; ++nc) {
      const int n = nh * 192 + ng * 96 + nc * 16 + lr;
      const float bias = b_proj[n];
#pragma unroll
      for (int reg = 0; reg < 4; ++reg) {
        const int row = rw * 16 + lg * 4 + reg;
        if (row < NTOK) {
          float* dst = (row >= P)
              ? x_out + ((size_t)(b * NWTOK + row - P)) * 384 + n
              : pbuf + ((size_t)(b * P + row)) * 384 + n;
          *dst = pacc[nc][reg] + bias;
        }
      }
    }
  }
}

// ---------------------------------------------------------------------------
// prompts_out = mean over 64 windows
// ---------------------------------------------------------------------------
__global__ __launch_bounds__(256) void reduce_prompts_kernel(
    const float* __restrict__ pbuf, float* __restrict__ po) {
  const int o = blockIdx.x * 256 + threadIdx.x;  // < 32*10*384
  const int b0 = o / 3840;
  const int rem = o - b0 * 3840;
  const float* base = pbuf + (size_t)b0 * 64 * 3840 + rem;
  float s = 0.f;
#pragma unroll 8
  for (int w = 0; w < 64; ++w) s += base[(size_t)w * 3840];
  po[o] = s * (1.f / 64.f);
}

extern "C" void kernel_launch(void* const* d_in, const int* in_sizes, int n_in,
                              void* d_out, int out_size, void* d_ws, size_t ws_size,
                              hipStream_t stream) {
  const float* x          = (const float*)d_in[0];
  const float* spa        = (const float*)d_in[1];
  const float* mask       = (const float*)d_in[2];
  const float* bias_table = (const float*)d_in[3];
  const float* w_qkv      = (const float*)d_in[4];
  const float* b_qkv      = (const float*)d_in[5];
  const float* w_proj     = (const float*)d_in[6];
  const float* b_proj     = (const float*)d_in[7];
  float* out = (float*)d_out;

  // ws layout (bytes):
  // [0, 77070336)            x_bf  (bf16 100352x384)  (consumed by gemm_qkv)
  // [77070336, 77316096)     xp_bf (bf16 320x384)
  // [77316096, 78200832)     wqkv_bf
  // [92798976, 324009984)    qkx (bf16 [2048][3][49][384])
  // [324009984, 324747264)   qkp (bf16 [32][3][10][384])
  // [324747264, 325042176)   wproj_bf
  // [325042176, 356499456)   pbuf  (f32 2048*10*384)
  // [356499456, 369082368)   combo (f32 [64][12][64][64])
  unsigned short* x_bf     = (unsigned short*)d_ws;
  unsigned short* xp_bf    = (unsigned short*)((char*)d_ws + 77070336ULL);
  unsigned short* wqkv_bf  = (unsigned short*)((char*)d_ws + 77316096ULL);
  unsigned short* qkx      = (unsigned short*)((char*)d_ws + 92798976ULL);
  unsigned short* qkp      = (unsigned short*)((char*)d_ws + 324009984ULL);
  unsigned short* wproj_bf = (unsigned short*)((char*)d_ws + 324747264ULL);
  float*          pbuf     = (float*)((char*)d_ws + 325042176ULL);
  float*          combo    = (float*)((char*)d_ws + 356499456ULL);

  convert_all_kernel<<<19164, 256, 0, stream>>>(x, spa, w_qkv, w_proj,
                                                x_bf, xp_bf, wqkv_bf, wproj_bf);
  combo_kernel<<<768, 256, 0, stream>>>(mask, bias_table, combo);
  gemm_qkv_kernel<<<9 * 787, 256, 0, stream>>>(x_bf, xp_bf, wqkv_bf, b_qkv,
                                               qkx, qkp);
  attn_proj_kernel<<<2048, 512, 0, stream>>>(qkx, qkp, combo, wproj_bf, b_proj,
                                             out + AW_OFF, out, pbuf);
  reduce_prompts_kernel<<<480, 256, 0, stream>>>(pbuf, out + PO_OFF);
}